// Round 13
// baseline (44.317 us; speedup 1.0000x reference)
//
#include <hip/hip_runtime.h>

// ---------------------------------------------------------------------------
// LeNet5-KAN on MI355X.  R13: conv2 split into bases-GEMM (kpad=8, 4 taps per
// MFMA K=32) + relu-GEMM (transposed R2 matrix, 3 MFMA/wave). 42% fewer
// conv2 MFMA/ds ops, LDS 30.6 KB -> 5 blocks/CU. Conv1 + fc unchanged (R11/12).
// MFMA f16 in / f32 accum; avg-pool folded into weights (stride-2 conv6x6).
//
//   A-frag: lane&15 = out px (M), lane>>4 = g = k-group (16B ds_read_b128)
//   B-frag: lane&15 = o (N),      lane>>4 = g = same k-group (16B global)
//   C     : col = lane&15 (o), row = g*4 + reg (px)
// A and B use the identical (g,i)->k map, so the MFMA-internal k permutation
// cancels. feat LDS chunks XOR-swizzled: ch ^= (ch>>3)&7 (regions 8-aligned).
//
// LDS chunk map (uint4 chunks): [0,1568) featA (conv1, 9-feat 2-chunk);
//   conv2 aliases: [0,864) feat2 (8 bases/elem), [864,1440) R2 [16px][36ch];
//   [1568,1784) h1l (864 f32); [1784,1912) rbuf (2x64 float4).  30592 B.
// ---------------------------------------------------------------------------

typedef _Float16 f16;
typedef f16 f16x8 __attribute__((ext_vector_type(8)));
typedef float f32x4 __attribute__((ext_vector_type(4)));

#define ONE_SIXTH 0.16666666666666666f

__device__ __forceinline__ void spline8_vals(float v, float* __restrict__ f) {
    float u  = 2.5f * v + 5.5f;
    bool valid = (u >= 0.0f) && (u < 11.0f);
    float fi = floorf(u);
    int   i  = (int)fi;
    float w  = u - fi;
    float omw = 1.0f - w;
    float w2 = w * w, w3 = w2 * w;
    float c0 = omw * omw * omw * ONE_SIXTH;
    float c1 = (3.0f * w3 - 6.0f * w2 + 4.0f) * ONE_SIXTH;
    float c2 = (-3.0f * w3 + 3.0f * w2 + 3.0f * w + 1.0f) * ONE_SIXTH;
    float c3 = w3 * ONE_SIXTH;
    int j0 = i - 3;
#pragma unroll
    for (int j = 0; j < 8; ++j) {
        int d = j - j0;
        float val = (d == 0) ? c0 : (d == 1) ? c1 : (d == 2) ? c2 : (d == 3) ? c3 : 0.0f;
        f[j] = valid ? val : 0.0f;
    }
}

// conv1 layout: two 16B chunks per elem: c0 = bases[0..7], c1 = {relu, 0 x7}
__device__ __forceinline__ void spline_chunks(float v, uint4& u0, uint4& u1) {
    float f[8];
    spline8_vals(v, f);
    union { f16 h[8]; uint4 u; } a, b;
#pragma unroll
    for (int j = 0; j < 8; ++j) a.h[j] = (f16)f[j];
    b.u.x = 0u; b.u.y = 0u; b.u.z = 0u; b.u.w = 0u;
    b.h[0] = (f16)fmaxf(v, 0.0f);
    u0 = a.u; u1 = b.u;
}

// conv2 layout: one 16B chunk per elem: bases[0..7] only
__device__ __forceinline__ uint4 spline8_chunk(float v) {
    float f[8];
    spline8_vals(v, f);
    union { f16 h[8]; uint4 u; } a;
#pragma unroll
    for (int j = 0; j < 8; ++j) a.h[j] = (f16)f[j];
    return a.u;
}

// ---------------------------------------------------------------------------
// K0: build pooled-conv weights, f16.
// W1g[(tap*16+o)*16+k], tap<36, o<16 (6 valid), k<16 (9 valid: 8 bases+relu)
// W2b[(ct*16+o)*8+k],  ct = c*36+t66 < 216, k<8 (bases only)
// W2rT[o*288+s]: s = wv*96 + i, i<72 -> base-weight(o, c=2wv+i/36, t66=i%36)
// pooled: w'[ey][ex] = 0.25 * sum_{a,b in {0,1}} w[ey-a][ex-b] (in-range)
// ---------------------------------------------------------------------------
__global__ __launch_bounds__(256) void k_prep(
    const float* __restrict__ c1_bw, const float* __restrict__ c1_sw,
    const float* __restrict__ c1_sc,
    const float* __restrict__ c2_bw, const float* __restrict__ c2_sw,
    const float* __restrict__ c2_sc,
    f16* __restrict__ W1g, f16* __restrict__ W2b, f16* __restrict__ W2rT)
{
    int t = blockIdx.x * 256 + threadIdx.x;
    if (t < 9216) {
        int tap = t >> 8, r = t & 255;
        int o = r >> 4, k = r & 15;
        float val = 0.0f;
        if (o < 6 && k < 9) {
            int ey = tap / 6, ex = tap - 6 * ey;
            float s = 0.0f;
            for (int a = 0; a < 2; ++a) {
                for (int b = 0; b < 2; ++b) {
                    int dy = ey - a, dx = ex - b;
                    if (dy >= 0 && dy < 5 && dx >= 0 && dx < 5) {
                        int idx = o * 25 + dy * 5 + dx;
                        s += (k == 8) ? c1_bw[idx] : c1_sw[idx * 8 + k] * c1_sc[idx];
                    }
                }
            }
            val = 0.25f * s;
        }
        W1g[t] = (f16)val;
    }
    if (t < 27648) {                      // W2b: bases only
        int ct = t >> 7, r = t & 127;
        int o = r >> 3, k = r & 7;
        int c = ct / 36, t66 = ct - c * 36;
        int ey = t66 / 6, ex = t66 - ey * 6;
        float s = 0.0f;
        for (int a = 0; a < 2; ++a) {
            for (int b = 0; b < 2; ++b) {
                int dy = ey - a, dx = ex - b;
                if (dy >= 0 && dy < 5 && dx >= 0 && dx < 5) {
                    int idx = o * 150 + c * 25 + dy * 5 + dx;
                    s += c2_sw[idx * 8 + k] * c2_sc[idx];
                }
            }
        }
        W2b[t] = (f16)(0.25f * s);
    }
    if (t < 4608) {                       // W2rT: relu (base) weights
        int o = t / 288, s = t - o * 288;
        int wq = s / 96, i = s - wq * 96;
        float val = 0.0f;
        if (i < 72) {
            int c = 2 * wq + (i >= 36 ? 1 : 0);
            int t66 = i - (i >= 36 ? 36 : 0);
            int ey = t66 / 6, ex = t66 - ey * 6;
            float acc = 0.0f;
            for (int a = 0; a < 2; ++a) {
                for (int b = 0; b < 2; ++b) {
                    int dy = ey - a, dx = ex - b;
                    if (dy >= 0 && dy < 5 && dx >= 0 && dx < 5)
                        acc += c2_bw[o * 150 + c * 25 + dy * 5 + dx];
                }
            }
            val = 0.25f * acc;
        }
        W2rT[t] = (f16)val;
    }
}

// ---------------------------------------------------------------------------
// K1: fused conv1+pool -> conv2+pool. One block = 1 image, 192 thr = 3 waves.
// ---------------------------------------------------------------------------
__global__ __launch_bounds__(192, 4) void k_conv12(
    const float* __restrict__ x, const f16* __restrict__ W1g,
    const f16* __restrict__ W2b, const f16* __restrict__ W2rT,
    float* __restrict__ h2)
{
    __shared__ uint4 feat[1912];

    const int img = blockIdx.x;
    const int tid = threadIdx.x;
    const int lane = tid & 63, wv = tid >> 6;
    const int ln15 = lane & 15, g = lane >> 4;
    const int gh = g & 1, gt = g >> 1;
    float* h1f = (float*)&feat[1568];

    // ---- Phase A: stage feat(x), loads issued first ----
    {
        float xv[5];
#pragma unroll
        for (int p = 0; p < 5; ++p) {
            int e = tid + p * 192;
            xv[p] = x[img * 784 + (e < 784 ? e : 783)];
        }
#pragma unroll
        for (int p = 0; p < 5; ++p) {
            int e = tid + p * 192;
            if (e < 784) {
                uint4 u0, u1;
                spline_chunks(xv[p], u0, u1);
                int ch = e * 2;
                int q = (ch >> 3) & 7;
                feat[ch ^ q] = u0;
                feat[(ch + 1) ^ q] = u1;
            }
        }
    }
    __syncthreads();

    // ---- Phase B: conv1, 18 kc unrolled, 4-deep prefetch ----
    {
        int ebase[3];
#pragma unroll
        for (int t = 0; t < 3; ++t) {
            int p = (wv * 3 + t) * 16 + ln15;
            int py = p / 12, px = p - py * 12;
            ebase[t] = py * 56 + px * 2;            // (2py)*28 + 2px
        }
        const f16* bbase = W1g + (gt * 16 + ln15) * 16 + gh * 8;  // + kc*512
        f16x8 wreg[4];
#pragma unroll
        for (int i = 0; i < 4; ++i)
            wreg[i] = *(const f16x8*)(bbase + i * 512);

        f32x4 acc[3] = {{0,0,0,0},{0,0,0,0},{0,0,0,0}};

#pragma unroll
        for (int kc = 0; kc < 18; ++kc) {
            f16x8 bcur = wreg[kc & 3];
            wreg[kc & 3] = *(const f16x8*)(bbase + (kc + 4) * 512); // overreads into W2b: safe
            int tap = kc * 2 + gt;
            int ey = (tap * 171) >> 10, ex = tap - ey * 6;
            int eoff = ey * 28 + ex;
#pragma unroll
            for (int t = 0; t < 3; ++t) {
                int ch = (ebase[t] + eoff) * 2 + gh;
                ch ^= (ch >> 3) & 7;
                f16x8 afrag = *(const f16x8*)(&feat[ch]);
                acc[t] = __builtin_amdgcn_mfma_f32_16x16x32_f16(afrag, bcur, acc[t], 0, 0, 0);
            }
        }
        if (ln15 < 6) {
#pragma unroll
            for (int t = 0; t < 3; ++t) {
                int p0 = (wv * 3 + t) * 16 + g * 4;     // row = g*4 + reg
                *(float4*)&h1f[ln15 * 144 + p0] =
                    make_float4(acc[t][0], acc[t][1], acc[t][2], acc[t][3]);
            }
        }
    }
    __syncthreads();    // featA reads done, h1l visible

    // ---- Phase C: build feat2 (bases) + R2 (relu transpose) from h1l ----
    {
        for (int e = tid; e < 864; e += 192) {
            uint4 u = spline8_chunk(h1f[e]);
            int ch = e; ch ^= (ch >> 3) & 7;
            feat[ch] = u;
        }
        for (int f = tid; f < 576; f += 192) {      // frag = (px p, chunk j)
            int p = f / 36, j = f - (f / 36) * 36;
            union { f16 h[8]; uint4 u; } r;
#pragma unroll
            for (int i = 0; i < 8; ++i) {
                int s = j * 8 + i;
                int wq = s / 96, ii = s - wq * 96;
                float v = 0.0f;
                if (ii < 72) {
                    int c = 2 * wq + (ii >= 36 ? 1 : 0);
                    int t66 = ii - (ii >= 36 ? 36 : 0);
                    int ey = (t66 * 171) >> 10, ex = t66 - ey * 6;
                    int epx2 = (p >> 2) * 24 + (p & 3) * 2;
                    v = fmaxf(h1f[c * 144 + epx2 + ey * 12 + ex], 0.0f);
                }
                r.h[i] = (f16)v;
            }
            int ch = 864 + p * 36 + j; ch ^= (ch >> 3) & 7;
            feat[ch] = r.u;
        }
    }
    __syncthreads();

    // ---- Phase D: conv2 = 18 bases-MFMA (4 taps each) + 3 relu-MFMA ----
    {
        const int epx2 = (ln15 >> 2) * 24 + (ln15 & 3) * 2;
        const f16* bb = W2b + (72 * wv + g) * 128 + ln15 * 8;   // + q*512
        f16x8 wreg[4];
#pragma unroll
        for (int i = 0; i < 4; ++i)
            wreg[i] = *(const f16x8*)(bb + i * 512);
        f16x8 rw[3];
#pragma unroll
        for (int r = 0; r < 3; ++r)
            rw[r] = *(const f16x8*)(W2rT + ln15 * 288 + wv * 96 + r * 32 + g * 8);

        f32x4 accA = {0, 0, 0, 0}, accB = {0, 0, 0, 0};

#pragma unroll
        for (int q = 0; q < 18; ++q) {
            f16x8 bcur = wreg[q & 3];
            wreg[q & 3] = *(const f16x8*)(bb + (q + 4) * 512);   // overread: in-ws
            int ct = 72 * wv + 4 * q + g;
            int c = ct / 36, t66 = ct - c * 36;
            int ey = (t66 * 171) >> 10, ex = t66 - ey * 6;
            int elem = c * 144 + epx2 + ey * 12 + ex;
            int ch = elem ^ ((elem >> 3) & 7);
            f16x8 afrag = *(const f16x8*)(&feat[ch]);
            if (q & 1)
                accB = __builtin_amdgcn_mfma_f32_16x16x32_f16(afrag, bcur, accB, 0, 0, 0);
            else
                accA = __builtin_amdgcn_mfma_f32_16x16x32_f16(afrag, bcur, accA, 0, 0, 0);
        }
#pragma unroll
        for (int r = 0; r < 3; ++r) {
            int ch = 864 + ln15 * 36 + wv * 12 + r * 4 + g;
            ch ^= (ch >> 3) & 7;
            f16x8 afrag = *(const f16x8*)(&feat[ch]);
            accA = __builtin_amdgcn_mfma_f32_16x16x32_f16(afrag, rw[r], accA, 0, 0, 0);
        }
        f32x4 acc = accA + accB;

        float4* rb2 = (float4*)&feat[1784];
        if (wv) rb2[(wv - 1) * 64 + lane] = make_float4(acc[0], acc[1], acc[2], acc[3]);
        __syncthreads();
        if (wv == 0) {
            float4 r0 = rb2[lane], r1 = rb2[64 + lane];
            *(float4*)&h2[img * 256 + ln15 * 16 + g * 4] =
                make_float4(acc[0] + r0.x + r1.x, acc[1] + r0.y + r1.y,
                            acc[2] + r0.z + r1.z, acc[3] + r0.w + r1.w);
        }
    }
}

// ---------------------------------------------------------------------------
// K3: fc1(relu) -> fc2(relu) -> fc3. Block = 4 batch rows, 256 threads,
// 256 blocks (1/CU). Weight rows L2-resident.
// ---------------------------------------------------------------------------
__global__ __launch_bounds__(256) void k_fc(
    const float* __restrict__ h2,
    const float* __restrict__ w1, const float* __restrict__ b1,
    const float* __restrict__ w2, const float* __restrict__ b2,
    const float* __restrict__ w3, const float* __restrict__ b3,
    float* __restrict__ out)
{
    __shared__ float xin[4][260];
    __shared__ float a1[4][120];
    __shared__ float a2[4][84];
    const int tid = threadIdx.x;
    const int r0 = blockIdx.x * 4;

    for (int i = tid; i < 1024; i += 256)
        xin[i >> 8][i & 255] = h2[r0 * 256 + i];
    __syncthreads();

    for (int idx = tid; idx < 480; idx += 256) {      // 120 out x 4 rows
        const int o = idx >> 2, r = idx & 3;
        const float* w = w1 + o * 256;
        float s = 0.0f;
#pragma unroll 8
        for (int k = 0; k < 64; ++k) {
            float4 wv = ((const float4*)w)[k];
            float4 xv = *(const float4*)(&xin[r][k * 4]);
            s += wv.x * xv.x + wv.y * xv.y + wv.z * xv.z + wv.w * xv.w;
        }
        a1[r][o] = fmaxf(s + b1[o], 0.0f);
    }
    __syncthreads();

    for (int idx = tid; idx < 336; idx += 256) {      // 84 out x 4 rows
        const int o = idx >> 2, r = idx & 3;
        const float* w = w2 + o * 120;
        float s = 0.0f;
#pragma unroll
        for (int k = 0; k < 30; ++k) {
            float4 wv = ((const float4*)w)[k];
            float4 xv = *(const float4*)(&a1[r][k * 4]);
            s += wv.x * xv.x + wv.y * xv.y + wv.z * xv.z + wv.w * xv.w;
        }
        a2[r][o] = fmaxf(s + b2[o], 0.0f);
    }
    __syncthreads();

    for (int idx = tid; idx < 248; idx += 256) {      // 62 out x 4 rows
        const int o = idx >> 2, r = idx & 3;
        const float* w = w3 + o * 84;
        float s = 0.0f;
#pragma unroll
        for (int k = 0; k < 21; ++k) {
            float4 wv = ((const float4*)w)[k];
            float4 xv = *(const float4*)(&a2[r][k * 4]);
            s += wv.x * xv.x + wv.y * xv.y + wv.z * xv.z + wv.w * xv.w;
        }
        out[(r0 + r) * 62 + o] = s + b3[o];
    }
}

// ---------------------------------------------------------------------------
extern "C" void kernel_launch(void* const* d_in, const int* in_sizes, int n_in,
                              void* d_out, int out_size, void* d_ws, size_t ws_size,
                              hipStream_t stream)
{
    (void)in_sizes; (void)n_in; (void)out_size; (void)ws_size;
    const float* x      = (const float*)d_in[0];
    const float* c1_bw  = (const float*)d_in[1];
    const float* c1_sw  = (const float*)d_in[2];
    const float* c1_sc  = (const float*)d_in[3];
    const float* c2_bw  = (const float*)d_in[4];
    const float* c2_sw  = (const float*)d_in[5];
    const float* c2_sc  = (const float*)d_in[6];
    const float* fc1_w  = (const float*)d_in[7];
    const float* fc1_b  = (const float*)d_in[8];
    const float* fc2_w  = (const float*)d_in[9];
    const float* fc2_b  = (const float*)d_in[10];
    const float* fc3_w  = (const float*)d_in[11];
    const float* fc3_b  = (const float*)d_in[12];
    float* out = (float*)d_out;

    char* wsb = (char*)d_ws;
    f16*   W1g  = (f16*)(wsb);                 //  9216 f16 @ 0
    f16*   W2b  = (f16*)(wsb + 18432);         // 27648 f16 @ 18432
    f16*   W2rT = (f16*)(wsb + 73728);         //  4608 f16 @ 73728
    float* h2   = (float*)(wsb + 98304);       // 1024*256 f32

    hipLaunchKernelGGL(k_prep, dim3(108), dim3(256), 0, stream,
                       c1_bw, c1_sw, c1_sc, c2_bw, c2_sw, c2_sc, W1g, W2b, W2rT);
    hipLaunchKernelGGL(k_conv12, dim3(1024), dim3(192), 0, stream,
                       x, W1g, W2b, W2rT, h2);
    hipLaunchKernelGGL(k_fc, dim3(256), dim3(256), 0, stream,
                       h2, fc1_w, fc1_b, fc2_w, fc2_b, fc3_w, fc3_b, out);
}

// Round 14
// 40.080 us; speedup vs baseline: 1.1057x; 1.1057x over previous
//
#include <hip/hip_runtime.h>

// ---------------------------------------------------------------------------
// LeNet5-KAN on MI355X.  R14: R12 phases, but 6 waves per 1-image block
// (384 thr) -> 24 waves/CU (6/SIMD) at unchanged ~36 KB LDS, doubling
// latency hiding for the ds_read->MFMA chains that R11-R13 showed are the
// limiter (VALUBusy 22%, all pipes idle).
// MFMA f16 in / f32 accum; avg-pool folded into weights (stride-2 conv6x6).
//
//   A-frag: lane&15 = out px, lane>>4 = k-group (16B ds_read_b128)
//   B-frag: lane&15 = o,     lane>>4 = same k-group (16B global load, L2)
//   C     : col = lane&15 (o), row = (lane>>4)*4 + reg
// feat LDS chunks (16B) XOR-swizzled: ch ^= (ch>>3)&7.
// ---------------------------------------------------------------------------

typedef _Float16 f16;
typedef f16 f16x8 __attribute__((ext_vector_type(8)));
typedef float f32x4 __attribute__((ext_vector_type(4)));

#define ONE_SIXTH 0.16666666666666666f

__device__ __forceinline__ void spline9(float v, float* __restrict__ f) {
    float u  = 2.5f * v + 5.5f;
    bool valid = (u >= 0.0f) && (u < 11.0f);
    float fi = floorf(u);
    int   i  = (int)fi;
    float w  = u - fi;
    float omw = 1.0f - w;
    float w2 = w * w, w3 = w2 * w;
    float c0 = omw * omw * omw * ONE_SIXTH;
    float c1 = (3.0f * w3 - 6.0f * w2 + 4.0f) * ONE_SIXTH;
    float c2 = (-3.0f * w3 + 3.0f * w2 + 3.0f * w + 1.0f) * ONE_SIXTH;
    float c3 = w3 * ONE_SIXTH;
    int j0 = i - 3;
#pragma unroll
    for (int j = 0; j < 8; ++j) {
        int d = j - j0;
        float val = (d == 0) ? c0 : (d == 1) ? c1 : (d == 2) ? c2 : (d == 3) ? c3 : 0.0f;
        f[j] = valid ? val : 0.0f;
    }
    f[8] = fmaxf(v, 0.0f);
}

// two 16B chunks: c0 = bases[0..7] as f16, c1 = {relu, 0 x7}
__device__ __forceinline__ void spline_chunks(float v, uint4& u0, uint4& u1) {
    float f[9];
    spline9(v, f);
    union { f16 h[8]; uint4 u; } a, b;
#pragma unroll
    for (int j = 0; j < 8; ++j) a.h[j] = (f16)f[j];
    b.u.x = 0u; b.u.y = 0u; b.u.z = 0u; b.u.w = 0u;
    b.h[0] = (f16)f[8];
    u0 = a.u; u1 = b.u;
}

// ---------------------------------------------------------------------------
// K0: build pooled-conv weights, f16 (unchanged from R9-R12).
// W1g[(tap*16+o)*16+k], tap<36, o<16 (6 valid), k<16 (9 valid)
// W2g[((c*36+tap)*16+o)*16+k], c<6
// w'[ey][ex] = 0.25 * sum_{a,b in {0,1}, in-range} w[ey-a][ex-b]
// ---------------------------------------------------------------------------
__global__ __launch_bounds__(256) void k_prep(
    const float* __restrict__ c1_bw, const float* __restrict__ c1_sw,
    const float* __restrict__ c1_sc,
    const float* __restrict__ c2_bw, const float* __restrict__ c2_sw,
    const float* __restrict__ c2_sc,
    f16* __restrict__ W1g, f16* __restrict__ W2g)
{
    int t = blockIdx.x * 256 + threadIdx.x;
    if (t < 9216) {
        int tap = t >> 8, r = t & 255;
        int o = r >> 4, k = r & 15;
        float val = 0.0f;
        if (o < 6 && k < 9) {
            int ey = tap / 6, ex = tap - 6 * ey;
            float s = 0.0f;
            for (int a = 0; a < 2; ++a) {
                for (int b = 0; b < 2; ++b) {
                    int dy = ey - a, dx = ex - b;
                    if (dy >= 0 && dy < 5 && dx >= 0 && dx < 5) {
                        int idx = o * 25 + dy * 5 + dx;
                        s += (k == 8) ? c1_bw[idx] : c1_sw[idx * 8 + k] * c1_sc[idx];
                    }
                }
            }
            val = 0.25f * s;
        }
        W1g[t] = (f16)val;
    }
    if (t < 55296) {
        int c = t / 9216, r = t - c * 9216;
        int tap = r >> 8, rr = r & 255;
        int o = rr >> 4, k = rr & 15;
        float val = 0.0f;
        if (k < 9) {
            int ey = tap / 6, ex = tap - 6 * ey;
            float s = 0.0f;
            for (int a = 0; a < 2; ++a) {
                for (int b = 0; b < 2; ++b) {
                    int dy = ey - a, dx = ex - b;
                    if (dy >= 0 && dy < 5 && dx >= 0 && dx < 5) {
                        int idx = o * 150 + c * 25 + dy * 5 + dx;
                        s += (k == 8) ? c2_bw[idx] : c2_sw[idx * 8 + k] * c2_sc[idx];
                    }
                }
            }
            val = 0.25f * s;
        }
        W2g[t] = (f16)val;
    }
}

// ---------------------------------------------------------------------------
// K1: fused conv1+pool -> conv2+pool. One block = 1 image, 384 thr = 6 waves.
// A: stage feat(x).           == barrier ==
// B: conv1 MFMA; waves 0-2 own tiles {wv,6+wv}, waves 3-5 own {wv}. == bar ==
// C: stage feat(h1).          == barrier ==
// D: conv2 MFMA; wave wv owns input channel c=wv (18 MFMA, dual chains);
//    6-way LDS reduce -> h2.
// ---------------------------------------------------------------------------
__global__ __launch_bounds__(384, 6) void k_conv12(
    const float* __restrict__ x, const f16* __restrict__ W1g,
    const f16* __restrict__ W2g, float* __restrict__ h2)
{
    __shared__ uint4  feat[1728];    // A: 1568 used; C: 1728 used (aliased)
    __shared__ float  h1l[864];      // conv1 output [o][144] f32
    __shared__ float4 rbuf[5][64];   // conv2 partial sums (waves 1-5)

    const int img = blockIdx.x;
    const int tid = threadIdx.x;
    const int lane = tid & 63, wv = tid >> 6;
    const int ln15 = lane & 15, g = lane >> 4;
    const int gh = g & 1, gt = g >> 1;

    // ---- Phase A: stage feat(x); loads issued first ----
    {
        float xv[3];
#pragma unroll
        for (int p = 0; p < 3; ++p) {
            int e = tid + p * 384;
            xv[p] = x[img * 784 + (e < 784 ? e : 783)];
        }
#pragma unroll
        for (int p = 0; p < 3; ++p) {
            int e = tid + p * 384;
            if (e < 784) {
                uint4 u0, u1;
                spline_chunks(xv[p], u0, u1);
                int ch = e * 2;
                int q = (ch >> 3) & 7;
                feat[ch ^ q] = u0;
                feat[(ch + 1) ^ q] = u1;
            }
        }
    }
    __syncthreads();

    // ---- Phase B: conv1; 18 kc unrolled, 4-deep prefetch, 1-2 tiles/wave --
    {
        const int nt = (wv < 3) ? 2 : 1;
        int ebase[2];
#pragma unroll
        for (int t = 0; t < 2; ++t) {
            int tile = (t == 0) ? wv : (6 + wv);
            int p = tile * 16 + ln15;
            int py = p / 12, px = p - py * 12;
            ebase[t] = py * 56 + px * 2;            // (2py)*28 + 2px
        }
        const f16* bbase = W1g + (gt * 16 + ln15) * 16 + gh * 8;  // + kc*512
        f16x8 wreg[4];
#pragma unroll
        for (int i = 0; i < 4; ++i)
            wreg[i] = *(const f16x8*)(bbase + i * 512);

        f32x4 acc[2] = {{0,0,0,0},{0,0,0,0}};

#pragma unroll
        for (int kc = 0; kc < 18; ++kc) {
            f16x8 bcur = wreg[kc & 3];
            wreg[kc & 3] = *(const f16x8*)(bbase + (kc + 4) * 512); // overreads into W2g: safe
            int tap = kc * 2 + gt;
            int ey = (tap * 171) >> 10, ex = tap - ey * 6;
            int eoff = ey * 28 + ex;
            {
                int ch = (ebase[0] + eoff) * 2 + gh;
                ch ^= (ch >> 3) & 7;
                f16x8 afrag = *(const f16x8*)(&feat[ch]);
                acc[0] = __builtin_amdgcn_mfma_f32_16x16x32_f16(afrag, bcur, acc[0], 0, 0, 0);
            }
            if (nt == 2) {                           // wave-uniform branch
                int ch = (ebase[1] + eoff) * 2 + gh;
                ch ^= (ch >> 3) & 7;
                f16x8 afrag = *(const f16x8*)(&feat[ch]);
                acc[1] = __builtin_amdgcn_mfma_f32_16x16x32_f16(afrag, bcur, acc[1], 0, 0, 0);
            }
        }
        if (ln15 < 6) {
            *(float4*)&h1l[ln15 * 144 + wv * 16 + g * 4] =
                make_float4(acc[0][0], acc[0][1], acc[0][2], acc[0][3]);
            if (nt == 2)
                *(float4*)&h1l[ln15 * 144 + (6 + wv) * 16 + g * 4] =
                    make_float4(acc[1][0], acc[1][1], acc[1][2], acc[1][3]);
        }
    }
    __syncthreads();    // featA reads done + h1l visible

    // ---- Phase C: stage feat(h1) ----
    {
        float hv[3];
#pragma unroll
        for (int p = 0; p < 3; ++p) {
            int e = tid + p * 384;
            hv[p] = h1l[e < 864 ? e : 863];
        }
#pragma unroll
        for (int p = 0; p < 3; ++p) {
            int e = tid + p * 384;
            if (e < 864) {
                uint4 u0, u1;
                spline_chunks(hv[p], u0, u1);
                int ch = e * 2;
                int q = (ch >> 3) & 7;
                feat[ch ^ q] = u0;
                feat[(ch + 1) ^ q] = u1;
            }
        }
    }
    __syncthreads();

    // ---- Phase D: conv2; wave wv owns channel c=wv; 18 kc, dual chains ----
    {
        const int py = ln15 >> 2, px = ln15 & 3;
        const int epx = py * 24 + px * 2;           // (2py)*12 + 2px
        // tap = 2i + gt of channel wv:
        const f16* bbase = W2g + (wv * 36 + gt) * 256 + ln15 * 16 + gh * 8;
        f16x8 wreg[4];
#pragma unroll
        for (int i = 0; i < 4; ++i)
            wreg[i] = *(const f16x8*)(bbase + i * 512);

        f32x4 accA = {0, 0, 0, 0}, accB = {0, 0, 0, 0};

#pragma unroll
        for (int i = 0; i < 18; ++i) {
            f16x8 bcur = wreg[i & 3];
            wreg[i & 3] = *(const f16x8*)(bbase + (i + 4) * 512); // overread: ws pad
            int tap = i * 2 + gt;
            int ey = (tap * 171) >> 10, ex = tap - ey * 6;
            int elem = wv * 144 + epx + ey * 12 + ex;
            int ch = elem * 2 + gh;
            ch ^= (ch >> 3) & 7;
            f16x8 afrag = *(const f16x8*)(&feat[ch]);
            if ((i & 1) == 0)
                accA = __builtin_amdgcn_mfma_f32_16x16x32_f16(afrag, bcur, accA, 0, 0, 0);
            else
                accB = __builtin_amdgcn_mfma_f32_16x16x32_f16(afrag, bcur, accB, 0, 0, 0);
        }
        f32x4 acc = accA + accB;

        if (wv) rbuf[wv - 1][lane] = make_float4(acc[0], acc[1], acc[2], acc[3]);
        __syncthreads();
        if (wv == 0) {
            float sx = acc[0], sy = acc[1], sz = acc[2], sw = acc[3];
#pragma unroll
            for (int r = 0; r < 5; ++r) {
                float4 rv = rbuf[r][lane];
                sx += rv.x; sy += rv.y; sz += rv.z; sw += rv.w;
            }
            *(float4*)&h2[img * 256 + ln15 * 16 + g * 4] =
                make_float4(sx, sy, sz, sw);
        }
    }
}

// ---------------------------------------------------------------------------
// K3: fc1(relu) -> fc2(relu) -> fc3. Block = 4 batch rows, 256 threads,
// 256 blocks (1/CU). Weight rows L2-resident.
// ---------------------------------------------------------------------------
__global__ __launch_bounds__(256) void k_fc(
    const float* __restrict__ h2,
    const float* __restrict__ w1, const float* __restrict__ b1,
    const float* __restrict__ w2, const float* __restrict__ b2,
    const float* __restrict__ w3, const float* __restrict__ b3,
    float* __restrict__ out)
{
    __shared__ float xin[4][260];
    __shared__ float a1[4][120];
    __shared__ float a2[4][84];
    const int tid = threadIdx.x;
    const int r0 = blockIdx.x * 4;

    for (int i = tid; i < 1024; i += 256)
        xin[i >> 8][i & 255] = h2[r0 * 256 + i];
    __syncthreads();

    for (int idx = tid; idx < 480; idx += 256) {      // 120 out x 4 rows
        const int o = idx >> 2, r = idx & 3;
        const float* w = w1 + o * 256;
        float s = 0.0f;
#pragma unroll 8
        for (int k = 0; k < 64; ++k) {
            float4 wv = ((const float4*)w)[k];
            float4 xv = *(const float4*)(&xin[r][k * 4]);
            s += wv.x * xv.x + wv.y * xv.y + wv.z * xv.z + wv.w * xv.w;
        }
        a1[r][o] = fmaxf(s + b1[o], 0.0f);
    }
    __syncthreads();

    for (int idx = tid; idx < 336; idx += 256) {      // 84 out x 4 rows
        const int o = idx >> 2, r = idx & 3;
        const float* w = w2 + o * 120;
        float s = 0.0f;
#pragma unroll
        for (int k = 0; k < 30; ++k) {
            float4 wv = ((const float4*)w)[k];
            float4 xv = *(const float4*)(&a1[r][k * 4]);
            s += wv.x * xv.x + wv.y * xv.y + wv.z * xv.z + wv.w * xv.w;
        }
        a2[r][o] = fmaxf(s + b2[o], 0.0f);
    }
    __syncthreads();

    for (int idx = tid; idx < 248; idx += 256) {      // 62 out x 4 rows
        const int o = idx >> 2, r = idx & 3;
        const float* w = w3 + o * 84;
        float s = 0.0f;
#pragma unroll
        for (int k = 0; k < 21; ++k) {
            float4 wv = ((const float4*)w)[k];
            float4 xv = *(const float4*)(&a2[r][k * 4]);
            s += wv.x * xv.x + wv.y * xv.y + wv.z * xv.z + wv.w * xv.w;
        }
        out[(r0 + r) * 62 + o] = s + b3[o];
    }
}

// ---------------------------------------------------------------------------
extern "C" void kernel_launch(void* const* d_in, const int* in_sizes, int n_in,
                              void* d_out, int out_size, void* d_ws, size_t ws_size,
                              hipStream_t stream)
{
    (void)in_sizes; (void)n_in; (void)out_size; (void)ws_size;
    const float* x      = (const float*)d_in[0];
    const float* c1_bw  = (const float*)d_in[1];
    const float* c1_sw  = (const float*)d_in[2];
    const float* c1_sc  = (const float*)d_in[3];
    const float* c2_bw  = (const float*)d_in[4];
    const float* c2_sw  = (const float*)d_in[5];
    const float* c2_sc  = (const float*)d_in[6];
    const float* fc1_w  = (const float*)d_in[7];
    const float* fc1_b  = (const float*)d_in[8];
    const float* fc2_w  = (const float*)d_in[9];
    const float* fc2_b  = (const float*)d_in[10];
    const float* fc3_w  = (const float*)d_in[11];
    const float* fc3_b  = (const float*)d_in[12];
    float* out = (float*)d_out;

    char* wsb = (char*)d_ws;
    f16*   W1g = (f16*)(wsb);                  //  9216 f16 = 18432 B
    f16*   W2g = (f16*)(wsb + 18432);          // 55296 f16 = 110592 B
    float* h2  = (float*)(wsb + 139264);       // 1024*256 f32 (8KB pad after
                                               // W2g for prefetch overread)

    hipLaunchKernelGGL(k_prep, dim3(256), dim3(256), 0, stream,
                       c1_bw, c1_sw, c1_sc, c2_bw, c2_sw, c2_sc, W1g, W2g);
    hipLaunchKernelGGL(k_conv12, dim3(1024), dim3(384), 0, stream,
                       x, W1g, W2g, h2);
    hipLaunchKernelGGL(k_fc, dim3(256), dim3(256), 0, stream,
                       h2, fc1_w, fc1_b, fc2_w, fc2_b, fc3_w, fc3_b, out);
}

// Round 15
// 39.145 us; speedup vs baseline: 1.1321x; 1.0239x over previous
//
#include <hip/hip_runtime.h>

// ---------------------------------------------------------------------------
// LeNet5-KAN on MI355X.  FINAL (= R12, best measured 39.1 us):
// per-wave PRIVATE staging regions remove the A->B and C->D barriers (only
// the h1 exchange barrier + reduce barrier remain). Wave wv stages input
// rows 8wv..8wv+11 (conv1 M-split) and h1 channels 2wv,2wv+1 (conv2 K-split)
// privately; same-wave LDS ordering is HW-guaranteed (in-order DS pipe).
// MFMA f16 in / f32 accum; avg-pool folded into weights (stride-2 conv6x6).
//
//   A-frag: lane&15 = out px, lane>>4 = k-group (16B ds_read_b128)
//   B-frag: lane&15 = o,     lane>>4 = same k-group (16B global load, L2)
//   C     : col = lane&15 (o), row = (lane>>4)*4 + reg
// feat LDS chunks (16B) XOR-swizzled: ch ^= (ch>>3)&7  (regions 8-chunk
// aligned: 672, 576 -> swizzle never crosses a region boundary).
//
// Optimization history (bench-verified):
//   R1 VALU conv 183us -> R5 f16-compress 125 -> R6 MFMA+pool-fold 51.6 ->
//   R7 conv1+conv2 fuse 45.6 -> R9 fc occupancy fix 39.8 -> R12 39.1.
//   Falsified: VMEM weights (R3), wide blocks (R8), fc-in-block (R10),
//   deeper prefetch (R11 null), fewer barriers (R12 null vs R9), K-pad
//   stripping (R13 regression), 2x waves (R14 null) -> fixed-floor plateau.
// ---------------------------------------------------------------------------

typedef _Float16 f16;
typedef f16 f16x8 __attribute__((ext_vector_type(8)));
typedef float f32x4 __attribute__((ext_vector_type(4)));

#define ONE_SIXTH 0.16666666666666666f

__device__ __forceinline__ void spline9(float v, float* __restrict__ f) {
    float u  = 2.5f * v + 5.5f;
    bool valid = (u >= 0.0f) && (u < 11.0f);
    float fi = floorf(u);
    int   i  = (int)fi;
    float w  = u - fi;
    float omw = 1.0f - w;
    float w2 = w * w, w3 = w2 * w;
    float c0 = omw * omw * omw * ONE_SIXTH;
    float c1 = (3.0f * w3 - 6.0f * w2 + 4.0f) * ONE_SIXTH;
    float c2 = (-3.0f * w3 + 3.0f * w2 + 3.0f * w + 1.0f) * ONE_SIXTH;
    float c3 = w3 * ONE_SIXTH;
    int j0 = i - 3;
#pragma unroll
    for (int j = 0; j < 8; ++j) {
        int d = j - j0;
        float val = (d == 0) ? c0 : (d == 1) ? c1 : (d == 2) ? c2 : (d == 3) ? c3 : 0.0f;
        f[j] = valid ? val : 0.0f;
    }
    f[8] = fmaxf(v, 0.0f);
}

// two 16B chunks: c0 = bases[0..7] as f16, c1 = {relu, 0 x7}
__device__ __forceinline__ void spline_chunks(float v, uint4& u0, uint4& u1) {
    float f[9];
    spline9(v, f);
    union { f16 h[8]; uint4 u; } a, b;
#pragma unroll
    for (int j = 0; j < 8; ++j) a.h[j] = (f16)f[j];
    b.u.x = 0u; b.u.y = 0u; b.u.z = 0u; b.u.w = 0u;
    b.h[0] = (f16)f[8];
    u0 = a.u; u1 = b.u;
}

// ---------------------------------------------------------------------------
// K0: build pooled-conv weights, f16.
// W1g[(tap*16+o)*16+k], tap<36, o<16 (6 valid), k<16 (9 valid)
// W2g[((c*36+tap)*16+o)*16+k], c<6
// w'[ey][ex] = 0.25 * sum_{a,b in {0,1}, in-range} w[ey-a][ex-b]
// ---------------------------------------------------------------------------
__global__ __launch_bounds__(256) void k_prep(
    const float* __restrict__ c1_bw, const float* __restrict__ c1_sw,
    const float* __restrict__ c1_sc,
    const float* __restrict__ c2_bw, const float* __restrict__ c2_sw,
    const float* __restrict__ c2_sc,
    f16* __restrict__ W1g, f16* __restrict__ W2g)
{
    int t = blockIdx.x * 256 + threadIdx.x;
    if (t < 9216) {
        int tap = t >> 8, r = t & 255;
        int o = r >> 4, k = r & 15;
        float val = 0.0f;
        if (o < 6 && k < 9) {
            int ey = tap / 6, ex = tap - 6 * ey;
            float s = 0.0f;
            for (int a = 0; a < 2; ++a) {
                for (int b = 0; b < 2; ++b) {
                    int dy = ey - a, dx = ex - b;
                    if (dy >= 0 && dy < 5 && dx >= 0 && dx < 5) {
                        int idx = o * 25 + dy * 5 + dx;
                        s += (k == 8) ? c1_bw[idx] : c1_sw[idx * 8 + k] * c1_sc[idx];
                    }
                }
            }
            val = 0.25f * s;
        }
        W1g[t] = (f16)val;
    }
    if (t < 55296) {
        int c = t / 9216, r = t - c * 9216;
        int tap = r >> 8, rr = r & 255;
        int o = rr >> 4, k = rr & 15;
        float val = 0.0f;
        if (k < 9) {
            int ey = tap / 6, ex = tap - 6 * ey;
            float s = 0.0f;
            for (int a = 0; a < 2; ++a) {
                for (int b = 0; b < 2; ++b) {
                    int dy = ey - a, dx = ex - b;
                    if (dy >= 0 && dy < 5 && dx >= 0 && dx < 5) {
                        int idx = o * 150 + c * 25 + dy * 5 + dx;
                        s += (k == 8) ? c2_bw[idx] : c2_sw[idx * 8 + k] * c2_sc[idx];
                    }
                }
            }
            val = 0.25f * s;
        }
        W2g[t] = (f16)val;
    }
}

// ---------------------------------------------------------------------------
// K1: fused conv1+pool -> conv2+pool. One block = 1 image, 192 thr = 3 waves.
// A(priv): wave stages its 12 input rows -> featA[wv*672 ..].
// B: conv1 MFMA (reads own region only) -> h1l (shared).   == barrier ==
// C(priv): wave stages h1 channels 2wv,2wv+1 -> featC[wv*576 ..].
// D: conv2 MFMA (own region, K-split) -> rbuf.             == barrier ==
// reduce -> h2.
// ---------------------------------------------------------------------------
__global__ __launch_bounds__(192, 3) void k_conv12(
    const float* __restrict__ x, const f16* __restrict__ W1g,
    const f16* __restrict__ W2g, float* __restrict__ h2)
{
    __shared__ uint4  feat[2016];    // A: [3][672]; C: [3][576] (aliased)
    __shared__ float  h1l[864];      // conv1 output [o][144] f32
    __shared__ float4 rbuf[2][64];   // conv2 partial sums (waves 1,2)

    const int img = blockIdx.x;
    const int tid = threadIdx.x;
    const int lane = tid & 63, wv = tid >> 6;
    const int ln15 = lane & 15, g = lane >> 4;
    const int gh = g & 1, gt = g >> 1;

    // ---- Phase A (private): stage rows 8wv..8wv+11 of x ----
    {
        const int r0 = 8 * wv;
        float xv[6];
#pragma unroll
        for (int p = 0; p < 6; ++p) {
            int e = lane + p * 64;
            int ee = e < 336 ? e : 335;
            int row = ee / 28, col = ee - row * 28;
            xv[p] = x[img * 784 + (r0 + row) * 28 + col];
        }
#pragma unroll
        for (int p = 0; p < 6; ++p) {
            int e = lane + p * 64;
            if (e < 336) {
                uint4 u0, u1;
                spline_chunks(xv[p], u0, u1);
                int ch = wv * 672 + e * 2;
                int q = (ch >> 3) & 7;
                feat[ch ^ q] = u0;
                feat[(ch + 1) ^ q] = u1;
            }
        }
    }
    // no barrier: B reads only this wave's region (in-order DS pipe)

    // ---- Phase B: conv1, 18 kc unrolled, 4-deep prefetch ----
    {
        int ebase[3];
#pragma unroll
        for (int t = 0; t < 3; ++t) {
            int p = (wv * 3 + t) * 16 + ln15;
            int py = p / 12, px = p - py * 12;
            int row_local = 2 * py - 8 * wv;        // 0,2,4,6
            ebase[t] = row_local * 28 + 2 * px;
        }
        const f16* bbase = W1g + (gt * 16 + ln15) * 16 + gh * 8;  // + kc*512
        f16x8 wreg[4];
#pragma unroll
        for (int i = 0; i < 4; ++i)
            wreg[i] = *(const f16x8*)(bbase + i * 512);

        f32x4 acc[3] = {{0,0,0,0},{0,0,0,0},{0,0,0,0}};

#pragma unroll
        for (int kc = 0; kc < 18; ++kc) {
            f16x8 bcur = wreg[kc & 3];
            wreg[kc & 3] = *(const f16x8*)(bbase + (kc + 4) * 512); // overreads into W2g: safe
            int tap = kc * 2 + gt;
            int ey = (tap * 171) >> 10, ex = tap - ey * 6;
            int eoff = ey * 28 + ex;
#pragma unroll
            for (int t = 0; t < 3; ++t) {
                int ch = wv * 672 + (ebase[t] + eoff) * 2 + gh;
                ch ^= (ch >> 3) & 7;
                f16x8 afrag = *(const f16x8*)(&feat[ch]);
                acc[t] = __builtin_amdgcn_mfma_f32_16x16x32_f16(afrag, bcur, acc[t], 0, 0, 0);
            }
        }
        if (ln15 < 6) {
#pragma unroll
            for (int t = 0; t < 3; ++t) {
                int p0 = (wv * 3 + t) * 16 + g * 4;     // row = g*4 + reg
                *(float4*)&h1l[ln15 * 144 + p0] =
                    make_float4(acc[t][0], acc[t][1], acc[t][2], acc[t][3]);
            }
        }
    }
    __syncthreads();    // h1l exchange + featA->featC alias protection

    // ---- Phase C (private): stage h1 channels 2wv, 2wv+1 ----
    {
        float hv[5];
#pragma unroll
        for (int p = 0; p < 5; ++p) {
            int e = lane + p * 64;
            int ee = e < 288 ? e : 287;
            hv[p] = h1l[wv * 288 + ee];         // h1l[(2wv)*144 + e]
        }
#pragma unroll
        for (int p = 0; p < 5; ++p) {
            int e = lane + p * 64;
            if (e < 288) {
                uint4 u0, u1;
                spline_chunks(hv[p], u0, u1);
                int ch = wv * 576 + e * 2;
                int q = (ch >> 3) & 7;
                feat[ch ^ q] = u0;
                feat[(ch + 1) ^ q] = u1;
            }
        }
    }
    // no barrier: D reads only this wave's region

    // ---- Phase D: conv2, K split over 3 waves, 4-deep prefetch, dual acc ----
    {
        const int py = ln15 >> 2, px = ln15 & 3;
        const int epx = py * 24 + px * 2;           // (2py)*12 + 2px
        const int kk0 = wv * 36;
        const f16* bbase = W2g + ((kk0 * 2 + gt) * 16 + ln15) * 16 + gh * 8;
        f16x8 wreg[4];
#pragma unroll
        for (int i = 0; i < 4; ++i)
            wreg[i] = *(const f16x8*)(bbase + i * 512);

        f32x4 accA = {0, 0, 0, 0}, accB = {0, 0, 0, 0};

#pragma unroll
        for (int i = 0; i < 36; ++i) {
            f16x8 bcur = wreg[i & 3];
            wreg[i & 3] = *(const f16x8*)(bbase + (i + 4) * 512); // overread: ws pad
            int cl = i / 18;                        // 0/1, literal after unroll
            int tk = i - cl * 18;
            int tap = tk * 2 + gt;
            int ey = (tap * 171) >> 10, ex = tap - ey * 6;
            int elem = cl * 144 + epx + ey * 12 + ex;
            int ch = wv * 576 + elem * 2 + gh;
            ch ^= (ch >> 3) & 7;
            f16x8 afrag = *(const f16x8*)(&feat[ch]);
            if ((i & 1) == 0)
                accA = __builtin_amdgcn_mfma_f32_16x16x32_f16(afrag, bcur, accA, 0, 0, 0);
            else
                accB = __builtin_amdgcn_mfma_f32_16x16x32_f16(afrag, bcur, accB, 0, 0, 0);
        }
        f32x4 acc = accA + accB;

        if (wv) rbuf[wv - 1][lane] = make_float4(acc[0], acc[1], acc[2], acc[3]);
        __syncthreads();
        if (wv == 0) {
            float4 r0 = rbuf[0][lane], r1 = rbuf[1][lane];
            *(float4*)&h2[img * 256 + ln15 * 16 + g * 4] =
                make_float4(acc[0] + r0.x + r1.x, acc[1] + r0.y + r1.y,
                            acc[2] + r0.z + r1.z, acc[3] + r0.w + r1.w);
        }
    }
}

// ---------------------------------------------------------------------------
// K3: fc1(relu) -> fc2(relu) -> fc3. Block = 4 batch rows, 256 threads,
// 256 blocks (1/CU). Weight rows L2-resident.
// ---------------------------------------------------------------------------
__global__ __launch_bounds__(256) void k_fc(
    const float* __restrict__ h2,
    const float* __restrict__ w1, const float* __restrict__ b1,
    const float* __restrict__ w2, const float* __restrict__ b2,
    const float* __restrict__ w3, const float* __restrict__ b3,
    float* __restrict__ out)
{
    __shared__ float xin[4][260];
    __shared__ float a1[4][120];
    __shared__ float a2[4][84];
    const int tid = threadIdx.x;
    const int r0 = blockIdx.x * 4;

    for (int i = tid; i < 1024; i += 256)
        xin[i >> 8][i & 255] = h2[r0 * 256 + i];
    __syncthreads();

    for (int idx = tid; idx < 480; idx += 256) {      // 120 out x 4 rows
        const int o = idx >> 2, r = idx & 3;
        const float* w = w1 + o * 256;
        float s = 0.0f;
#pragma unroll 8
        for (int k = 0; k < 64; ++k) {
            float4 wv = ((const float4*)w)[k];
            float4 xv = *(const float4*)(&xin[r][k * 4]);
            s += wv.x * xv.x + wv.y * xv.y + wv.z * xv.z + wv.w * xv.w;
        }
        a1[r][o] = fmaxf(s + b1[o], 0.0f);
    }
    __syncthreads();

    for (int idx = tid; idx < 336; idx += 256) {      // 84 out x 4 rows
        const int o = idx >> 2, r = idx & 3;
        const float* w = w2 + o * 120;
        float s = 0.0f;
#pragma unroll
        for (int k = 0; k < 30; ++k) {
            float4 wv = ((const float4*)w)[k];
            float4 xv = *(const float4*)(&a1[r][k * 4]);
            s += wv.x * xv.x + wv.y * xv.y + wv.z * xv.z + wv.w * xv.w;
        }
        a2[r][o] = fmaxf(s + b2[o], 0.0f);
    }
    __syncthreads();

    for (int idx = tid; idx < 248; idx += 256) {      // 62 out x 4 rows
        const int o = idx >> 2, r = idx & 3;
        const float* w = w3 + o * 84;
        float s = 0.0f;
#pragma unroll
        for (int k = 0; k < 21; ++k) {
            float4 wv = ((const float4*)w)[k];
            float4 xv = *(const float4*)(&a2[r][k * 4]);
            s += wv.x * xv.x + wv.y * xv.y + wv.z * xv.z + wv.w * xv.w;
        }
        out[(r0 + r) * 62 + o] = s + b3[o];
    }
}

// ---------------------------------------------------------------------------
extern "C" void kernel_launch(void* const* d_in, const int* in_sizes, int n_in,
                              void* d_out, int out_size, void* d_ws, size_t ws_size,
                              hipStream_t stream)
{
    (void)in_sizes; (void)n_in; (void)out_size; (void)ws_size;
    const float* x      = (const float*)d_in[0];
    const float* c1_bw  = (const float*)d_in[1];
    const float* c1_sw  = (const float*)d_in[2];
    const float* c1_sc  = (const float*)d_in[3];
    const float* c2_bw  = (const float*)d_in[4];
    const float* c2_sw  = (const float*)d_in[5];
    const float* c2_sc  = (const float*)d_in[6];
    const float* fc1_w  = (const float*)d_in[7];
    const float* fc1_b  = (const float*)d_in[8];
    const float* fc2_w  = (const float*)d_in[9];
    const float* fc2_b  = (const float*)d_in[10];
    const float* fc3_w  = (const float*)d_in[11];
    const float* fc3_b  = (const float*)d_in[12];
    float* out = (float*)d_out;

    char* wsb = (char*)d_ws;
    f16*   W1g = (f16*)(wsb);                  //  9216 f16 = 18432 B
    f16*   W2g = (f16*)(wsb + 18432);          // 55296 f16 = 110592 B
    float* h2  = (float*)(wsb + 139264);       // 1024*256 f32 (8KB pad after
                                               // W2g for prefetch overread)

    hipLaunchKernelGGL(k_prep, dim3(256), dim3(256), 0, stream,
                       c1_bw, c1_sw, c1_sc, c2_bw, c2_sw, c2_sc, W1g, W2g);
    hipLaunchKernelGGL(k_conv12, dim3(1024), dim3(192), 0, stream,
                       x, W1g, W2g, h2);
    hipLaunchKernelGGL(k_fc, dim3(256), dim3(256), 0, stream,
                       h2, fc1_w, fc1_b, fc2_w, fc2_b, fc3_w, fc3_b, out);
}